// Round 1
// baseline (222.147 us; speedup 1.0000x reference)
//
#include <hip/hip_runtime.h>
#include <stdint.h>

#define Bb 8
#define Hh 128
#define Ww 128
#define Aa 8
#define Cc 8
#define Nn 131072           // H*W*A
#define PREK 1024
#define POSTK 300
#define NBIN 120            // scores 9..127 -> bin = s-9
#define NCHUNK 512          // Nn / 256

__device__ __forceinline__ float clampb(float v){ return fminf(fmaxf(v, 0.0f), 1024.0f); }

// K1: per-(b,n) best score over 8 classes; store int8 score; per-chunk histogram of valid scores
__global__ void k1_scores(const int* __restrict__ data, signed char* __restrict__ sc8,
                          int* __restrict__ chist){
    int blk = blockIdx.x;            // B*512 = 4096 blocks, one 256-item chunk each
    int b = blk >> 9, ci = blk & 511;
    int h = ci >> 2, w0 = (ci & 3) << 5;
    int tid = threadIdx.x;           // 256
    int a = tid >> 5, wl = tid & 31;
    int w = w0 + wl;
    const int* p = data + ((size_t)b*96 + a*12 + 4)*16384 + h*128 + w;
    int best = p[0];
#pragma unroll
    for (int c = 1; c < 8; ++c) best = max(best, p[c*16384]);
    sc8[(size_t)b*Nn + ci*256 + (wl*8 + a)] = (signed char)best;

    __shared__ int hist[NBIN];
    if (tid < NBIN) hist[tid] = 0;
    __syncthreads();
    if (best >= 9) atomicAdd(&hist[best-9], 1);
    __syncthreads();
    if (tid < NBIN) chist[((b*NCHUNK) + ci)*NBIN + tid] = hist[tid];
}

// K2: per batch: global hist, suffix counts gt[], cutoff bin T; init topidx = -1
__global__ void k2_select(const int* __restrict__ chist, int* __restrict__ gt,
                          int* __restrict__ Tb_, int* __restrict__ topidx){
    int b = blockIdx.x, tid = threadIdx.x;   // 256
    __shared__ int hs[NBIN];
    if (tid < NBIN){
        int s = 0;
        for (int ch = 0; ch < NCHUNK; ++ch) s += chist[((b*NCHUNK)+ch)*NBIN + tid];
        hs[tid] = s;
    }
    __syncthreads();
    if (tid == 0){
        int cum = 0, T = 0, found = 0;
        for (int bin = NBIN-1; bin >= 0; --bin){
            gt[b*128 + bin] = cum;
            cum += hs[bin];
            if (cum >= PREK){ T = bin; found = 1; break; }
        }
        if (!found) T = 0;
        Tb_[b] = T;
    }
    for (int k = tid; k < PREK; k += 256) topidx[b*PREK + k] = -1;
}

// K2b: exclusive prefix over chunks, in place, only for bins >= T
__global__ void k2b_scan(int* __restrict__ chist, const int* __restrict__ Tb_){
    int b = blockIdx.x, bin = threadIdx.x;   // 128
    if (bin >= NBIN) return;
    if (bin < Tb_[b]) return;
    int run = 0;
    for (int ch = 0; ch < NCHUNK; ++ch){
        int idx = ((b*NCHUNK)+ch)*NBIN + bin;
        int v = chist[idx]; chist[idx] = run; run += v;
    }
}

// K3: stable rank for each candidate with s >= T; scatter into topidx/topsc
__global__ void k3_rank(const signed char* __restrict__ sc8, const int* __restrict__ chist,
                        const int* __restrict__ gt, const int* __restrict__ Tb_,
                        int* __restrict__ topidx, int* __restrict__ topsc){
    int blk = blockIdx.x; int b = blk >> 9, ci = blk & 511; int tid = threadIdx.x;
    __shared__ signed char sc[256];
    int s = sc8[(size_t)b*Nn + ci*256 + tid];
    sc[tid] = (signed char)s;
    __syncthreads();
    int T = Tb_[b];
    int bin = s - 9;
    if (bin < T) return;                 // also rejects s < 9 (T >= 0)
    int eq = 0;
    for (int j = 0; j < tid; ++j) eq += (sc[j] == (signed char)s);
    int rank = gt[b*128 + bin] + chist[((b*NCHUNK)+ci)*NBIN + bin] + eq;
    if (rank < PREK){
        topidx[b*PREK + rank] = ci*256 + tid;
        topsc[b*PREK + rank]  = s;
    }
}

// K4: decode boxes + argmax label + float score for the selected candidates (bit-exact f32)
__global__ void k4_decode(const int* __restrict__ data, const float* __restrict__ anchors,
                          const int* __restrict__ etab, const int* __restrict__ topidx,
                          const int* __restrict__ topsc, float4* __restrict__ bk,
                          int* __restrict__ lab, float* __restrict__ scf){
    int g = blockIdx.x*256 + threadIdx.x;
    if (g >= Bb*PREK) return;
    int b = g >> 10;
    int n = topidx[g];
    if (n < 0){ bk[g] = make_float4(0.f,0.f,0.f,0.f); lab[g] = -1; scf[g] = 0.f; return; }
    int a = n & 7, hw = n >> 3, h = hw >> 7, w = hw & 127;
    const int* p = data + ((size_t)b*96 + a*12)*16384 + h*128 + w;
    int d0 = p[0], d1 = p[16384], d2 = p[2*16384], d3 = p[3*16384];
    int best = topsc[g];
    int label = 0;
#pragma unroll
    for (int c = 7; c >= 0; --c){ if (p[(4+c)*16384] == best) label = c; }   // first argmax
    float4 an = ((const float4*)anchors)[n];
    float cx = __fmul_rn(__fadd_rn(an.x, an.z), 0.5f);
    float cy = __fmul_rn(__fadd_rn(an.y, an.w), 0.5f);
    float wx = __fsub_rn(an.z, an.x), wy = __fsub_rn(an.w, an.y);
    float dx = __fmul_rn((float)d0, 0.0625f), dy = __fmul_rn((float)d1, 0.0625f);
    float ex = __fmul_rn((float)etab[d2+128], 0.0625f);
    float ey = __fmul_rn((float)etab[d3+128], 0.0625f);
    float pcx = __fadd_rn(cx, __fmul_rn(dx, wx));
    float pcy = __fadd_rn(cy, __fmul_rn(dy, wy));
    float hx = __fmul_rn(__fmul_rn(wx, ex), 0.5f);
    float hy = __fmul_rn(__fmul_rn(wy, ey), 0.5f);
    float x1 = clampb(__fsub_rn(pcx, hx)), y1 = clampb(__fsub_rn(pcy, hy));
    float x2 = clampb(__fadd_rn(pcx, hx)), y2 = clampb(__fadd_rn(pcy, hy));
    bk[g] = make_float4(x1, y1, x2, y2);
    lab[g] = label;
    scf[g] = __fmul_rn((float)best, 0.0625f);
}

// K4b: per batch, stable partition of the 1024 ranked entries into per-class lists
__global__ void __launch_bounds__(1024) k4b_part(const int* __restrict__ lab, int* __restrict__ cidx,
                                                 int* __restrict__ ccnt, int* __restrict__ keep){
    int b = blockIdx.x; int k = threadIdx.x;  // 1024
    __shared__ signed char sl[PREK];
    __shared__ int cnt[8];
    int l = lab[b*PREK + k];
    sl[k] = (signed char)l;
    if (k < 8) cnt[k] = 0;
    keep[b*PREK + k] = 0;
    __syncthreads();
    if (l >= 0){
        int pos = 0;
        for (int j = 0; j < k; ++j) pos += (sl[j] == (signed char)l);
        cidx[((b*8 + l) << 10) + pos] = k;
        atomicAdd(&cnt[l], 1);
    }
    __syncthreads();
    if (k < 8) ccnt[b*8 + k] = cnt[k];
}

// K5: greedy NMS per (batch,class); one wave per block; boxes in LDS with class offset (bit-exact)
__global__ void __launch_bounds__(64) k5_nms(const float4* __restrict__ bk, const int* __restrict__ cidx,
                                             const int* __restrict__ ccnt, int* __restrict__ keep){
    int bc = blockIdx.x; int b = bc >> 3, c = bc & 7;
    int lane = threadIdx.x;
    int M = ccnt[bc];
    if (M <= 0) return;
    __shared__ float X1[PREK], Y1[PREK], X2[PREK], Y2[PREK], AR[PREK];
    __shared__ int KL[PREK];
    __shared__ unsigned char SUP[PREK];
    float off = 4096.0f * (float)c;
    for (int m = lane; m < M; m += 64){
        int k = cidx[(bc << 10) + m];
        float4 bb = bk[b*PREK + k];
        float x1 = __fadd_rn(bb.x, off), y1 = __fadd_rn(bb.y, off);
        float x2 = __fadd_rn(bb.z, off), y2 = __fadd_rn(bb.w, off);
        X1[m]=x1; Y1[m]=y1; X2[m]=x2; Y2[m]=y2;
        AR[m] = __fmul_rn(__fsub_rn(x2,x1), __fsub_rn(y2,y1));
        KL[m]=k; SUP[m]=0;
    }
    __syncthreads();
    for (int i = 0; i < M; ++i){
        if (SUP[i]) continue;                       // wave-uniform LDS broadcast
        float xi1=X1[i], yi1=Y1[i], xi2=X2[i], yi2=Y2[i], ai=AR[i];
        for (int j = i + 1 + lane; j < M; j += 64){
            if (SUP[j]) continue;
            float wx = fmaxf(__fsub_rn(fminf(xi2, X2[j]), fmaxf(xi1, X1[j])), 0.0f);
            float wy = fmaxf(__fsub_rn(fminf(yi2, Y2[j]), fmaxf(yi1, Y1[j])), 0.0f);
            float inter = __fmul_rn(wx, wy);
            float den = __fadd_rn(__fsub_rn(__fadd_rn(ai, AR[j]), inter), 1e-9f);
            if (__fdiv_rn(inter, den) > 0.5f) SUP[j] = 1;
        }
    }
    for (int m = lane; m < M; m += 64) if (!SUP[m]) keep[b*PREK + KL[m]] = 1;
}

// K6: per batch, compact kept entries in rank order, emit first 300 (+ zero pads)
__global__ void __launch_bounds__(1024) k6_out(const float4* __restrict__ bk, const int* __restrict__ lab,
                                               const float* __restrict__ scf, const int* __restrict__ keep,
                                               float* __restrict__ out){
    int b = blockIdx.x; int tid = threadIdx.x;   // 1024
    __shared__ int wcnt[16];
    __shared__ int totS;
    int l = lab[b*PREK + tid];
    bool kp = (l >= 0) && (keep[b*PREK + tid] != 0);
    unsigned long long ball = __ballot(kp);
    int lane = tid & 63, wv = tid >> 6;
    int within = __popcll(ball & ((1ull << lane) - 1ull));
    if (lane == 0) wcnt[wv] = __popcll(ball);
    __syncthreads();
    if (tid == 0){
        int r = 0;
        for (int wq = 0; wq < 16; ++wq){ int t = wcnt[wq]; wcnt[wq] = r; r += t; }
        totS = r;
    }
    __syncthreads();
    int pos = wcnt[wv] + within;
    float* boxes  = out;                 // (8,300,4)
    float* scores = out + Bb*POSTK*4;    // (8,300)
    float* labs   = out + Bb*POSTK*5;    // (8,300), int values stored as f32
    if (kp && pos < POSTK){
        float4 bb = bk[b*PREK + tid];
        int o = (b*POSTK + pos)*4;
        boxes[o+0]=bb.x; boxes[o+1]=bb.y; boxes[o+2]=bb.z; boxes[o+3]=bb.w;
        scores[b*POSTK + pos] = scf[b*PREK + tid];
        labs[b*POSTK + pos] = (float)l;
    }
    int tot = totS; if (tot > POSTK) tot = POSTK;
    if (tid >= tot && tid < POSTK){
        int o = (b*POSTK + tid)*4;
        boxes[o+0]=0.f; boxes[o+1]=0.f; boxes[o+2]=0.f; boxes[o+3]=0.f;
        scores[b*POSTK + tid] = 0.f;
        labs[b*POSTK + tid] = -1.0f;
    }
}

extern "C" void kernel_launch(void* const* d_in, const int* in_sizes, int n_in,
                              void* d_out, int out_size, void* d_ws, size_t ws_size,
                              hipStream_t stream) {
    const int*   data    = (const int*)d_in[0];
    const float* anchors = (const float*)d_in[1];
    const int*   etab    = (const int*)d_in[2];
    float* out = (float*)d_out;

    char* ws = (char*)d_ws;
    size_t off = 0;
    auto alloc = [&](size_t bytes)->char*{ char* p = ws + off; off += (bytes + 255) & ~(size_t)255; return p; };
    signed char* sc8  = (signed char*)alloc((size_t)Bb*Nn);            // 1.0 MB
    int* chist        = (int*)alloc((size_t)Bb*NCHUNK*NBIN*4);         // 1.9 MB
    int* gt           = (int*)alloc((size_t)Bb*128*4);
    int* Tb_          = (int*)alloc((size_t)Bb*4);
    int* topidx       = (int*)alloc((size_t)Bb*PREK*4);
    int* topsc        = (int*)alloc((size_t)Bb*PREK*4);
    float4* bk        = (float4*)alloc((size_t)Bb*PREK*16);
    int* lab          = (int*)alloc((size_t)Bb*PREK*4);
    float* scf        = (float*)alloc((size_t)Bb*PREK*4);
    int* cidx         = (int*)alloc((size_t)Bb*8*PREK*4);
    int* ccnt         = (int*)alloc((size_t)Bb*8*4);
    int* keep         = (int*)alloc((size_t)Bb*PREK*4);
    (void)ws_size; (void)in_sizes; (void)n_in; (void)out_size;

    k1_scores<<<Bb*NCHUNK, 256, 0, stream>>>(data, sc8, chist);
    k2_select<<<Bb, 256, 0, stream>>>(chist, gt, Tb_, topidx);
    k2b_scan<<<Bb, 128, 0, stream>>>(chist, Tb_);
    k3_rank<<<Bb*NCHUNK, 256, 0, stream>>>(sc8, chist, gt, Tb_, topidx, topsc);
    k4_decode<<<(Bb*PREK + 255)/256, 256, 0, stream>>>(data, anchors, etab, topidx, topsc, bk, lab, scf);
    k4b_part<<<Bb, 1024, 0, stream>>>(lab, cidx, ccnt, keep);
    k5_nms<<<Bb*Cc, 64, 0, stream>>>(bk, cidx, ccnt, keep);
    k6_out<<<Bb, 1024, 0, stream>>>(bk, lab, scf, keep, out);
}